// Round 2
// baseline (974.253 us; speedup 1.0000x reference)
//
#include <hip/hip_runtime.h>
#include <hip/hip_bf16.h>

#define N_NODE   100000
#define N_EDGE   1600000
#define IN_DIM   128
#define HID1     64
#define HID2     64
#define OUT_DIM  32
#define NUM_GRAPHS 256

// ---------------- graph preprocessing ----------------

__global__ __launch_bounds__(256)
void k_deg(const int* __restrict__ snd, const int* __restrict__ rcv,
           int* __restrict__ degS, int* __restrict__ degR) {
    int e = blockIdx.x * 256 + threadIdx.x;
    if (e < N_EDGE) {
        atomicAdd(&degS[snd[e]], 1);
        atomicAdd(&degR[rcv[e]], 1);
    }
}

__global__ __launch_bounds__(1024)
void k_scan(const int* __restrict__ degR, int* __restrict__ rowptr) {
    __shared__ int s[1024];
    const int t = threadIdx.x;
    const int CH = (N_NODE + 1023) / 1024;
    int beg = t * CH, end = min(beg + CH, N_NODE);
    int sum = 0;
    for (int i = beg; i < end; ++i) sum += degR[i];
    s[t] = sum;
    __syncthreads();
    for (int off = 1; off < 1024; off <<= 1) {
        int v = (t >= off) ? s[t - off] : 0;
        __syncthreads();
        s[t] += v;
        __syncthreads();
    }
    int run = s[t] - sum;                 // exclusive prefix of this chunk
    for (int i = beg; i < end; ++i) { rowptr[i] = run; run += degR[i]; }
    if (t == 1023) rowptr[N_NODE] = s[1023];
}

__global__ __launch_bounds__(256)
void k_norm(const int* __restrict__ degS, const int* __restrict__ degR,
            float* __restrict__ normS, float* __restrict__ normR) {
    int i = blockIdx.x * 256 + threadIdx.x;
    if (i < N_NODE) {
        normS[i] = rsqrtf(fmaxf((float)degS[i], 1.0f));
        normR[i] = rsqrtf(fmaxf((float)degR[i], 1.0f));
    }
}

__global__ __launch_bounds__(256)
void k_scatter(const int* __restrict__ snd, const int* __restrict__ rcv,
               const int* __restrict__ rowptr, int* __restrict__ fill,
               int* __restrict__ sortedSrc) {
    int e = blockIdx.x * 256 + threadIdx.x;
    if (e < N_EDGE) {
        int r = rcv[e];
        int pos = rowptr[r] + atomicAdd(&fill[r], 1);
        sortedSrc[pos] = snd[e];
    }
}

// ---------------- dense transform: Y[n,:] = (X[n,:] @ W + b) * normS[n] ----------------

template<int IN, int OUT, int NPB>
__global__ __launch_bounds__(256)
void k_gemm(const float* __restrict__ X, const float* __restrict__ W,
            const float* __restrict__ bias, const float* __restrict__ normS,
            float* __restrict__ Y) {
    __shared__ float Wl[IN * OUT];
    __shared__ float bl[OUT];
    __shared__ float xs[NPB * IN];
    const int tid = threadIdx.x;
    for (int i = tid; i < IN * OUT; i += 256) Wl[i] = W[i];
    if (tid < OUT) bl[tid] = bias[tid];
    const int base = blockIdx.x * NPB;
    for (int i = tid; i < NPB * IN; i += 256) {
        int node = base + i / IN;
        xs[i] = (node < N_NODE) ? X[node * IN + (i % IN)] : 0.0f;
    }
    __syncthreads();
    const int wave = tid >> 6, lane = tid & 63;
    const int SUB = 64 / OUT;           // nodes handled simultaneously per wave (1 or 2)
    const int j = lane % OUT;
    const int sub = lane / OUT;
    const int NPW = NPB / 4;            // nodes per wave
    for (int nl = 0; nl < NPW; nl += SUB) {
        int nodeLocal = wave * NPW + nl + sub;
        int node = base + nodeLocal;
        if (node >= N_NODE) continue;
        float acc = bl[j];
        const float* xr = &xs[nodeLocal * IN];
        #pragma unroll 8
        for (int k = 0; k < IN; ++k) acc += xr[k] * Wl[k * OUT + j];
        Y[node * OUT + j] = acc * normS[node];
    }
}

// ---------------- aggregation: Y[n,:] = act(normR[n] * sum_{e in row n} H[src[e],:]) ----------------

template<int F, bool RELU>
__global__ __launch_bounds__(256)
void k_agg(const float* __restrict__ H, const int* __restrict__ rowptr,
           const int* __restrict__ srcs, const float* __restrict__ normR,
           float* __restrict__ Y) {
    const int node = (blockIdx.x * 256 + threadIdx.x) >> 6;
    const int lane = threadIdx.x & 63;
    if (node >= N_NODE) return;
    const int start = rowptr[node], end = rowptr[node + 1];
    const int P = 64 / F;               // edges processed in parallel (1 or 2)
    const int p = lane / F, j = lane % F;
    float acc = 0.0f;
    int e = start + p;
    for (; e + 3 * P < end; e += 4 * P) {
        int s0 = srcs[e], s1 = srcs[e + P], s2 = srcs[e + 2 * P], s3 = srcs[e + 3 * P];
        float v0 = H[s0 * F + j], v1 = H[s1 * F + j];
        float v2 = H[s2 * F + j], v3 = H[s3 * F + j];
        acc += v0; acc += v1; acc += v2; acc += v3;
    }
    for (; e < end; e += P) acc += H[srcs[e] * F + j];
    if (P == 2) acc += __shfl_down(acc, 32);
    float r = acc * normR[node];
    if (RELU) r = fmaxf(r, 0.0f);
    if (lane < F) Y[node * F + j] = r;
}

// ---------------- graph pooling ----------------

__global__ __launch_bounds__(256)
void k_pool(const float* __restrict__ H, const int* __restrict__ batch,
            float* __restrict__ out) {
    int idx = blockIdx.x * 256 + threadIdx.x;
    if (idx >= N_NODE * OUT_DIM) return;
    int node = idx >> 5;        // /32
    int j = idx & 31;
    atomicAdd(&out[batch[node] * OUT_DIM + j], H[node * OUT_DIM + j]);
}

// ---------------- launch ----------------

extern "C" void kernel_launch(void* const* d_in, const int* in_sizes, int n_in,
                              void* d_out, int out_size, void* d_ws, size_t ws_size,
                              hipStream_t stream) {
    const float* x   = (const float*)d_in[0];
    const float* W1  = (const float*)d_in[1];
    const float* b1  = (const float*)d_in[2];
    const float* W2  = (const float*)d_in[3];
    const float* b2  = (const float*)d_in[4];
    const float* W3  = (const float*)d_in[5];
    const float* b3  = (const float*)d_in[6];
    const int* snd   = (const int*)d_in[7];
    const int* rcv   = (const int*)d_in[8];
    const int* batch = (const int*)d_in[9];
    float* out = (float*)d_out;

    char* ws = (char*)d_ws;
    size_t off = 0;
    auto carve = [&](size_t bytes) { char* p = ws + off; off += (bytes + 15) & ~size_t(15); return p; };
    int*   degS      = (int*)  carve(N_NODE * 4);
    int*   degR      = (int*)  carve(N_NODE * 4);
    int*   fill      = (int*)  carve(N_NODE * 4);
    int*   rowptr    = (int*)  carve((N_NODE + 1) * 4);
    int*   sortedSrc = (int*)  carve(N_EDGE * 4);
    float* normS     = (float*)carve(N_NODE * 4);
    float* normR     = (float*)carve(N_NODE * 4);
    float* bufA      = (float*)carve(N_NODE * 64 * 4);
    float* bufB      = (float*)carve(N_NODE * 64 * 4);

    // zero histograms/fill (contiguous at ws start) and the output accumulator
    hipMemsetAsync(d_ws, 0, 3 * ((N_NODE * 4 + 15) & ~size_t(15)), stream);
    hipMemsetAsync(d_out, 0, NUM_GRAPHS * OUT_DIM * 4, stream);

    const int EB = (N_EDGE + 255) / 256;
    k_deg<<<EB, 256, 0, stream>>>(snd, rcv, degS, degR);
    k_scan<<<1, 1024, 0, stream>>>(degR, rowptr);
    k_norm<<<(N_NODE + 255) / 256, 256, 0, stream>>>(degS, degR, normS, normR);
    k_scatter<<<EB, 256, 0, stream>>>(snd, rcv, rowptr, fill, sortedSrc);

    const int AGG_B = (N_NODE * 64 + 255) / 256;   // one wave per node

    // layer 1: 128 -> 64, relu
    k_gemm<IN_DIM, HID1, 16><<<(N_NODE + 15) / 16, 256, 0, stream>>>(x, W1, b1, normS, bufA);
    k_agg<HID1, true><<<AGG_B, 256, 0, stream>>>(bufA, rowptr, sortedSrc, normR, bufB);

    // layer 2: 64 -> 64, relu
    k_gemm<HID1, HID2, 16><<<(N_NODE + 15) / 16, 256, 0, stream>>>(bufB, W2, b2, normS, bufA);
    k_agg<HID2, true><<<AGG_B, 256, 0, stream>>>(bufA, rowptr, sortedSrc, normR, bufB);

    // layer 3: 64 -> 32, no relu
    k_gemm<HID2, OUT_DIM, 32><<<(N_NODE + 31) / 32, 256, 0, stream>>>(bufB, W3, b3, normS, bufA);
    k_agg<OUT_DIM, false><<<AGG_B, 256, 0, stream>>>(bufA, rowptr, sortedSrc, normR, bufB);

    // pooling
    k_pool<<<(N_NODE * OUT_DIM + 255) / 256, 256, 0, stream>>>(bufB, batch, out);
}

// Round 3
// 739.702 us; speedup vs baseline: 1.3171x; 1.3171x over previous
//
#include <hip/hip_runtime.h>
#include <hip/hip_bf16.h>

#define N_NODE   100000
#define N_EDGE   1600000
#define IN_DIM   128
#define HID1     64
#define HID2     64
#define OUT_DIM  32
#define NUM_GRAPHS 256

#define SCAN_BLOCKS ((N_NODE + 255) / 256)   // 391

// ---------------- graph preprocessing ----------------

__global__ __launch_bounds__(256)
void k_deg(const int* __restrict__ snd, const int* __restrict__ rcv,
           int* __restrict__ degS, int* __restrict__ degR) {
    int e = blockIdx.x * 256 + threadIdx.x;
    if (e < N_EDGE) {
        atomicAdd(&degS[snd[e]], 1);
        atomicAdd(&degR[rcv[e]], 1);
    }
}

// per-block degree sums + degree-norm factors (fused old k_norm)
__global__ __launch_bounds__(256)
void k_blocksum_norm(const int* __restrict__ degS, const int* __restrict__ degR,
                     int* __restrict__ partials,
                     float* __restrict__ normS, float* __restrict__ normR) {
    const int t = threadIdx.x;
    const int i = blockIdx.x * 256 + t;
    int dR = 0;
    if (i < N_NODE) {
        dR = degR[i];
        int dS = degS[i];
        normS[i] = rsqrtf(fmaxf((float)dS, 1.0f));
        normR[i] = rsqrtf(fmaxf((float)dR, 1.0f));
    }
    int v = dR;
    #pragma unroll
    for (int o = 1; o < 64; o <<= 1) v += __shfl_xor(v, o);
    __shared__ int sw[4];
    if ((t & 63) == 0) sw[t >> 6] = v;
    __syncthreads();
    if (t == 0) partials[blockIdx.x] = sw[0] + sw[1] + sw[2] + sw[3];
}

// rowptr[i] = exclusive prefix of degR; rowptr[N_NODE] = N_EDGE
__global__ __launch_bounds__(256)
void k_rowptr(const int* __restrict__ degR, const int* __restrict__ partials,
              int* __restrict__ rowptr) {
    const int b = blockIdx.x, t = threadIdx.x;
    const int i = b * 256 + t;
    const int lane = t & 63, wave = t >> 6;
    int deg = (i < N_NODE) ? degR[i] : 0;
    // sum of partials[0..b) distributed across the block
    int ps = 0;
    for (int j = t; j < b; j += 256) ps += partials[j];
    #pragma unroll
    for (int o = 1; o < 64; o <<= 1) ps += __shfl_xor(ps, o);
    __shared__ int sPre[4];
    __shared__ int sWave[4];
    if (lane == 0) sPre[wave] = ps;
    // wave-level inclusive scan of deg
    int inc = deg;
    #pragma unroll
    for (int o = 1; o < 64; o <<= 1) { int n = __shfl_up(inc, o); if (lane >= o) inc += n; }
    if (lane == 63) sWave[wave] = inc;
    __syncthreads();
    int blockPrefix = sPre[0] + sPre[1] + sPre[2] + sPre[3];
    int waveOff = 0;
    for (int w = 0; w < wave; ++w) waveOff += sWave[w];
    int excl = blockPrefix + waveOff + inc - deg;
    if (i < N_NODE) rowptr[i] = excl;
    if (i == N_NODE - 1) rowptr[N_NODE] = excl + deg;
}

__global__ __launch_bounds__(256)
void k_scatter(const int* __restrict__ snd, const int* __restrict__ rcv,
               const int* __restrict__ rowptr, int* __restrict__ fill,
               int* __restrict__ sortedSrc) {
    int e = blockIdx.x * 256 + threadIdx.x;
    if (e < N_EDGE) {
        int r = rcv[e];
        int pos = rowptr[r] + atomicAdd(&fill[r], 1);
        sortedSrc[pos] = snd[e];
    }
}

// ---------------- dense transform: Y[n,:] = (X[n,:] @ W + b) * normS[n] ----------------

template<int IN, int OUT, int NPB>
__global__ __launch_bounds__(256)
void k_gemm(const float* __restrict__ X, const float* __restrict__ W,
            const float* __restrict__ bias, const float* __restrict__ normS,
            float* __restrict__ Y) {
    __shared__ float Wl[IN * OUT];
    __shared__ float bl[OUT];
    __shared__ float xs[NPB * IN];
    const int tid = threadIdx.x;
    for (int i = tid; i < IN * OUT; i += 256) Wl[i] = W[i];
    if (tid < OUT) bl[tid] = bias[tid];
    const int base = blockIdx.x * NPB;
    for (int i = tid; i < NPB * IN; i += 256) {
        int node = base + i / IN;
        xs[i] = (node < N_NODE) ? X[node * IN + (i % IN)] : 0.0f;
    }
    __syncthreads();
    const int wave = tid >> 6, lane = tid & 63;
    const int SUB = 64 / OUT;           // nodes handled simultaneously per wave (1 or 2)
    const int j = lane % OUT;
    const int sub = lane / OUT;
    const int NPW = NPB / 4;            // nodes per wave
    for (int nl = 0; nl < NPW; nl += SUB) {
        int nodeLocal = wave * NPW + nl + sub;
        int node = base + nodeLocal;
        if (node >= N_NODE) continue;
        float acc = bl[j];
        const float* xr = &xs[nodeLocal * IN];
        #pragma unroll 8
        for (int k = 0; k < IN; ++k) acc += xr[k] * Wl[k * OUT + j];
        Y[node * OUT + j] = acc * normS[node];
    }
}

// ---------------- aggregation: Y[n,:] = act(normR[n] * sum_{e in row n} H[src[e],:]) ----------------

template<int F, bool RELU>
__global__ __launch_bounds__(256)
void k_agg(const float* __restrict__ H, const int* __restrict__ rowptr,
           const int* __restrict__ srcs, const float* __restrict__ normR,
           float* __restrict__ Y) {
    const int node = (blockIdx.x * 256 + threadIdx.x) >> 6;
    const int lane = threadIdx.x & 63;
    if (node >= N_NODE) return;
    const int start = rowptr[node], end = rowptr[node + 1];
    const int P = 64 / F;               // edges processed in parallel (1 or 2)
    const int p = lane / F, j = lane % F;
    float acc = 0.0f;
    int e = start + p;
    for (; e + 3 * P < end; e += 4 * P) {
        int s0 = srcs[e], s1 = srcs[e + P], s2 = srcs[e + 2 * P], s3 = srcs[e + 3 * P];
        float v0 = H[s0 * F + j], v1 = H[s1 * F + j];
        float v2 = H[s2 * F + j], v3 = H[s3 * F + j];
        acc += v0; acc += v1; acc += v2; acc += v3;
    }
    for (; e < end; e += P) acc += H[srcs[e] * F + j];
    if (P == 2) acc += __shfl_down(acc, 32);
    float r = acc * normR[node];
    if (RELU) r = fmaxf(r, 0.0f);
    if (lane < F) Y[node * F + j] = r;
}

// ---------------- graph pooling (batch is sorted -> run-based accumulation) ----------------

__global__ __launch_bounds__(256)
void k_pool(const float* __restrict__ H, const int* __restrict__ batch,
            float* __restrict__ out) {
    const int wid = (blockIdx.x * 256 + threadIdx.x) >> 6;
    const int lane = threadIdx.x & 63;
    const int NWAVE = 1024;
    const int NPW = (N_NODE + NWAVE - 1) / NWAVE;      // 98 nodes per wave
    int n0 = wid * NPW, n1 = min(n0 + NPW, N_NODE);
    if (n0 >= n1) return;
    const int j = lane & 31, p = lane >> 5;            // 2 nodes in flight per wave
    float acc = 0.0f;
    int gCur = -1;
    for (int n = n0 + p; n < n1; n += 2) {
        int g = batch[n];
        float v = H[n * OUT_DIM + j];
        if (g != gCur) {
            if (gCur >= 0) atomicAdd(&out[gCur * OUT_DIM + j], acc);
            acc = v; gCur = g;
        } else {
            acc += v;
        }
    }
    if (gCur >= 0) atomicAdd(&out[gCur * OUT_DIM + j], acc);
}

// ---------------- launch ----------------

extern "C" void kernel_launch(void* const* d_in, const int* in_sizes, int n_in,
                              void* d_out, int out_size, void* d_ws, size_t ws_size,
                              hipStream_t stream) {
    const float* x   = (const float*)d_in[0];
    const float* W1  = (const float*)d_in[1];
    const float* b1  = (const float*)d_in[2];
    const float* W2  = (const float*)d_in[3];
    const float* b2  = (const float*)d_in[4];
    const float* W3  = (const float*)d_in[5];
    const float* b3  = (const float*)d_in[6];
    const int* snd   = (const int*)d_in[7];
    const int* rcv   = (const int*)d_in[8];
    const int* batch = (const int*)d_in[9];
    float* out = (float*)d_out;

    char* ws = (char*)d_ws;
    size_t off = 0;
    auto carve = [&](size_t bytes) { char* p = ws + off; off += (bytes + 15) & ~size_t(15); return p; };
    int*   degS      = (int*)  carve(N_NODE * 4);
    int*   degR      = (int*)  carve(N_NODE * 4);
    int*   fill      = (int*)  carve(N_NODE * 4);
    int*   rowptr    = (int*)  carve((N_NODE + 1) * 4);
    int*   partials  = (int*)  carve(SCAN_BLOCKS * 4);
    int*   sortedSrc = (int*)  carve(N_EDGE * 4);
    float* normS     = (float*)carve(N_NODE * 4);
    float* normR     = (float*)carve(N_NODE * 4);
    float* bufA      = (float*)carve(N_NODE * 64 * 4);
    float* bufB      = (float*)carve(N_NODE * 64 * 4);

    // zero histograms/fill (contiguous at ws start) and the output accumulator
    hipMemsetAsync(d_ws, 0, 3 * ((N_NODE * 4 + 15) & ~size_t(15)), stream);
    hipMemsetAsync(d_out, 0, NUM_GRAPHS * OUT_DIM * 4, stream);

    const int EB = (N_EDGE + 255) / 256;
    k_deg<<<EB, 256, 0, stream>>>(snd, rcv, degS, degR);
    k_blocksum_norm<<<SCAN_BLOCKS, 256, 0, stream>>>(degS, degR, partials, normS, normR);
    k_rowptr<<<SCAN_BLOCKS, 256, 0, stream>>>(degR, partials, rowptr);
    k_scatter<<<EB, 256, 0, stream>>>(snd, rcv, rowptr, fill, sortedSrc);

    const int AGG_B = (N_NODE * 64 + 255) / 256;   // one wave per node

    // layer 1: 128 -> 64, relu
    k_gemm<IN_DIM, HID1, 16><<<(N_NODE + 15) / 16, 256, 0, stream>>>(x, W1, b1, normS, bufA);
    k_agg<HID1, true><<<AGG_B, 256, 0, stream>>>(bufA, rowptr, sortedSrc, normR, bufB);

    // layer 2: 64 -> 64, relu
    k_gemm<HID1, HID2, 16><<<(N_NODE + 15) / 16, 256, 0, stream>>>(bufB, W2, b2, normS, bufA);
    k_agg<HID2, true><<<AGG_B, 256, 0, stream>>>(bufA, rowptr, sortedSrc, normR, bufB);

    // layer 3: 64 -> 32, no relu
    k_gemm<HID2, OUT_DIM, 32><<<(N_NODE + 31) / 32, 256, 0, stream>>>(bufB, W3, b3, normS, bufA);
    k_agg<OUT_DIM, false><<<AGG_B, 256, 0, stream>>>(bufA, rowptr, sortedSrc, normR, bufB);

    // pooling
    k_pool<<<256, 256, 0, stream>>>(bufB, batch, out);
}

// Round 4
// 615.755 us; speedup vs baseline: 1.5822x; 1.2013x over previous
//
#include <hip/hip_runtime.h>
#include <hip/hip_bf16.h>

#define N_NODE   100000
#define N_EDGE   1600000
#define IN_DIM   128
#define HID1     64
#define HID2     64
#define OUT_DIM  32
#define NUM_GRAPHS 256
#define NCOPY    8

#define SCAN_BLOCKS ((N_NODE + 255) / 256)   // 391
#define EB2 (N_EDGE / 512)                   // 3125 blocks, 2 edges/thread, exact

typedef unsigned int uint;

__device__ __forceinline__ float bflo(uint p) { return __uint_as_float(p << 16); }
__device__ __forceinline__ float bfhi(uint p) { return __uint_as_float(p & 0xFFFF0000u); }
__device__ __forceinline__ uint bfpack(float a, float b) {
    uint ua = __float_as_uint(a), ub = __float_as_uint(b);
    ua = (ua + 0x7FFFu + ((ua >> 16) & 1u)) >> 16;          // RNE -> low 16
    ub = (ub + 0x7FFFu + ((ub >> 16) & 1u)) & 0xFFFF0000u;  // RNE -> high 16
    return ua | ub;
}

// ---------------- preprocessing ----------------
// pass1: replicated histograms (8 copies -> ~8x less same-line atomic serialization)
// + record per-copy position of each edge (counting-sort pos-trick, no scatter atomics later)

__global__ __launch_bounds__(256)
void k_pass1(const int2* __restrict__ snd2, const int2* __restrict__ rcv2,
             int* __restrict__ degS8, int* __restrict__ degR8, uint2* __restrict__ posP) {
    const int gid = blockIdx.x * 256 + threadIdx.x;
    const int c = blockIdx.x & (NCOPY - 1);
    int2 s = snd2[gid], r = rcv2[gid];
    int* dS = degS8 + c * N_NODE;
    int* dR = degR8 + c * N_NODE;
    atomicAdd(&dS[s.x], 1);
    atomicAdd(&dS[s.y], 1);
    uint p0 = (uint)atomicAdd(&dR[r.x], 1);
    uint p1 = (uint)atomicAdd(&dR[r.y], 1);
    posP[gid] = make_uint2((p0 << 17) | (uint)r.x, (p1 << 17) | (uint)r.y);
}

// reduce copies -> degR, per-copy exclusive bases, norm factors, per-block partial sums
__global__ __launch_bounds__(256)
void k_reduce(const int* __restrict__ degS8, const int* __restrict__ degR8,
              int* __restrict__ degR, unsigned char* __restrict__ base8,
              float* __restrict__ normS, float* __restrict__ normR,
              int* __restrict__ partials) {
    const int t = threadIdx.x;
    const int i = blockIdx.x * 256 + t;
    int totR = 0;
    if (i < N_NODE) {
        int accR = 0, accS = 0;
        #pragma unroll
        for (int c = 0; c < NCOPY; ++c) {
            base8[c * N_NODE + i] = (unsigned char)accR;
            accR += degR8[c * N_NODE + i];
            accS += degS8[c * N_NODE + i];
        }
        degR[i] = accR; totR = accR;
        normS[i] = rsqrtf(fmaxf((float)accS, 1.0f));
        normR[i] = rsqrtf(fmaxf((float)accR, 1.0f));
    }
    int v = totR;
    #pragma unroll
    for (int o = 1; o < 64; o <<= 1) v += __shfl_xor(v, o);
    __shared__ int sw[4];
    if ((t & 63) == 0) sw[t >> 6] = v;
    __syncthreads();
    if (t == 0) partials[blockIdx.x] = sw[0] + sw[1] + sw[2] + sw[3];
}

// rowptr[i] = exclusive prefix of degR; rowptr[N_NODE] = N_EDGE
__global__ __launch_bounds__(256)
void k_rowptr(const int* __restrict__ degR, const int* __restrict__ partials,
              int* __restrict__ rowptr) {
    const int b = blockIdx.x, t = threadIdx.x;
    const int i = b * 256 + t;
    const int lane = t & 63, wave = t >> 6;
    int deg = (i < N_NODE) ? degR[i] : 0;
    int ps = 0;
    for (int j = t; j < b; j += 256) ps += partials[j];
    #pragma unroll
    for (int o = 1; o < 64; o <<= 1) ps += __shfl_xor(ps, o);
    __shared__ int sPre[4];
    __shared__ int sWave[4];
    if (lane == 0) sPre[wave] = ps;
    int inc = deg;
    #pragma unroll
    for (int o = 1; o < 64; o <<= 1) { int n = __shfl_up(inc, o); if (lane >= o) inc += n; }
    if (lane == 63) sWave[wave] = inc;
    __syncthreads();
    int blockPrefix = sPre[0] + sPre[1] + sPre[2] + sPre[3];
    int waveOff = 0;
    for (int w = 0; w < wave; ++w) waveOff += sWave[w];
    int excl = blockPrefix + waveOff + inc - deg;
    if (i < N_NODE) rowptr[i] = excl;
    if (i == N_NODE - 1) rowptr[N_NODE] = excl + deg;
}

// pass2: place edges (atomic-free)
__global__ __launch_bounds__(256)
void k_pass2(const int2* __restrict__ snd2, const uint2* __restrict__ posP,
             const int* __restrict__ rowptr, const unsigned char* __restrict__ base8,
             int* __restrict__ sortedSrc) {
    const int gid = blockIdx.x * 256 + threadIdx.x;
    const int c = blockIdx.x & (NCOPY - 1);
    int2 s = snd2[gid];
    uint2 pp = posP[gid];
    int r0 = (int)(pp.x & 0x1FFFFu), p0 = (int)(pp.x >> 17);
    int r1 = (int)(pp.y & 0x1FFFFu), p1 = (int)(pp.y >> 17);
    sortedSrc[rowptr[r0] + (int)base8[c * N_NODE + r0] + p0] = s.x;
    sortedSrc[rowptr[r1] + (int)base8[c * N_NODE + r1] + p1] = s.y;
}

// ---------------- dense transforms (fp32 accumulate, bf16 packed output) ----------------

template<int IN, int OUT, int NPB>
__global__ __launch_bounds__(256)
void k_gemm_f32(const float* __restrict__ X, const float* __restrict__ W,
                const float* __restrict__ bias, const float* __restrict__ normS,
                uint* __restrict__ Y2) {
    __shared__ float Wl[IN * OUT];
    __shared__ float bl[OUT];
    __shared__ float xs[NPB * IN];
    const int tid = threadIdx.x;
    for (int i = tid; i < IN * OUT; i += 256) Wl[i] = W[i];
    if (tid < OUT) bl[tid] = bias[tid];
    const int base = blockIdx.x * NPB;
    for (int i = tid; i < NPB * IN; i += 256) {
        int node = base + i / IN;
        xs[i] = (node < N_NODE) ? X[node * IN + (i % IN)] : 0.0f;
    }
    __syncthreads();
    const int wave = tid >> 6, lane = tid & 63;
    const int SUB = 64 / OUT;
    const int j = lane % OUT;
    const int sub = lane / OUT;
    const int NPW = NPB / 4;
    for (int nl = 0; nl < NPW; nl += SUB) {
        int nodeLocal = wave * NPW + nl + sub;
        int node = base + nodeLocal;
        float acc = bl[j];
        const float* xr = &xs[nodeLocal * IN];
        #pragma unroll 8
        for (int k = 0; k < IN; ++k) acc += xr[k] * Wl[k * OUT + j];
        float a = acc * ((node < N_NODE) ? normS[node] : 0.0f);
        float b = __shfl_down(a, 1);
        if (node < N_NODE && (j & 1) == 0) Y2[node * (OUT / 2) + (j >> 1)] = bfpack(a, b);
    }
}

template<int IN, int OUT, int NPB>
__global__ __launch_bounds__(256)
void k_gemm_bf16(const uint* __restrict__ X2, const float* __restrict__ W,
                 const float* __restrict__ bias, const float* __restrict__ normS,
                 uint* __restrict__ Y2) {
    __shared__ float Wl[IN * OUT];
    __shared__ float bl[OUT];
    __shared__ float xs[NPB * IN];
    const int tid = threadIdx.x;
    for (int i = tid; i < IN * OUT; i += 256) Wl[i] = W[i];
    if (tid < OUT) bl[tid] = bias[tid];
    const int base = blockIdx.x * NPB;
    const int IN2 = IN / 2;
    for (int i = tid; i < NPB * IN2; i += 256) {
        int node = base + i / IN2;
        uint p = (node < N_NODE) ? X2[node * IN2 + (i % IN2)] : 0u;
        ((float2*)xs)[i] = make_float2(bflo(p), bfhi(p));
    }
    __syncthreads();
    const int wave = tid >> 6, lane = tid & 63;
    const int SUB = 64 / OUT;
    const int j = lane % OUT;
    const int sub = lane / OUT;
    const int NPW = NPB / 4;
    for (int nl = 0; nl < NPW; nl += SUB) {
        int nodeLocal = wave * NPW + nl + sub;
        int node = base + nodeLocal;
        float acc = bl[j];
        const float* xr = &xs[nodeLocal * IN];
        #pragma unroll 8
        for (int k = 0; k < IN; ++k) acc += xr[k] * Wl[k * OUT + j];
        float a = acc * ((node < N_NODE) ? normS[node] : 0.0f);
        float b = __shfl_down(a, 1);
        if (node < N_NODE && (j & 1) == 0) Y2[node * (OUT / 2) + (j >> 1)] = bfpack(a, b);
    }
}

// ---------------- aggregation: Y[n,:] = act(normR[n] * sum_e H[src[e],:]) ; bf16 in/out ----------------

template<int F, bool RELU>
__global__ __launch_bounds__(256)
void k_agg(const uint* __restrict__ H2, const int* __restrict__ rowptr,
           const int* __restrict__ srcs, const float* __restrict__ normR,
           uint* __restrict__ Y2) {
    const int node = (blockIdx.x * 256 + threadIdx.x) >> 6;
    const int lane = threadIdx.x & 63;
    const int F2 = F / 2;                 // uints per row
    const int PE = 64 / F2;               // edges in flight (2 for F=64, 4 for F=32)
    const int sub = lane / F2;
    const int fj = lane % F2;
    const int start = rowptr[node], end = rowptr[node + 1];
    float a0 = 0.0f, a1 = 0.0f;
    int e = start + sub;
    for (; e + 3 * PE < end; e += 4 * PE) {
        int s0 = srcs[e], s1 = srcs[e + PE], s2 = srcs[e + 2 * PE], s3 = srcs[e + 3 * PE];
        uint p0 = H2[s0 * F2 + fj];
        uint p1 = H2[s1 * F2 + fj];
        uint p2 = H2[s2 * F2 + fj];
        uint p3 = H2[s3 * F2 + fj];
        a0 += bflo(p0); a1 += bfhi(p0);
        a0 += bflo(p1); a1 += bfhi(p1);
        a0 += bflo(p2); a1 += bfhi(p2);
        a0 += bflo(p3); a1 += bfhi(p3);
    }
    for (; e < end; e += PE) {
        uint p = H2[srcs[e] * F2 + fj];
        a0 += bflo(p); a1 += bfhi(p);
    }
    if (PE == 4) { a0 += __shfl_xor(a0, 16); a1 += __shfl_xor(a1, 16); }
    a0 += __shfl_xor(a0, 32); a1 += __shfl_xor(a1, 32);
    if (lane < F2) {
        float nr = normR[node];
        float r0 = a0 * nr, r1 = a1 * nr;
        if (RELU) { r0 = fmaxf(r0, 0.0f); r1 = fmaxf(r1, 0.0f); }
        Y2[node * F2 + fj] = bfpack(r0, r1);
    }
}

// ---------------- graph pooling (batch sorted -> run-based accumulation) ----------------

__global__ __launch_bounds__(256)
void k_pool(const uint* __restrict__ H2, const int* __restrict__ batch,
            float* __restrict__ out) {
    const int wid = (blockIdx.x * 256 + threadIdx.x) >> 6;
    const int lane = threadIdx.x & 63;
    const int NPW = (N_NODE + 1023) / 1024;            // 98
    int n0 = wid * NPW, n1 = min(n0 + NPW, N_NODE);
    const int p = lane >> 4, fj = lane & 15;           // 4 node streams x 16 feature-pairs
    float a0 = 0.0f, a1 = 0.0f;
    int gCur = -1;
    for (int n = n0 + p; n < n1; n += 4) {
        int g = batch[n];
        uint v = H2[n * 16 + fj];
        if (g != gCur) {
            if (gCur >= 0) {
                atomicAdd(&out[gCur * OUT_DIM + 2 * fj], a0);
                atomicAdd(&out[gCur * OUT_DIM + 2 * fj + 1], a1);
            }
            gCur = g; a0 = bflo(v); a1 = bfhi(v);
        } else {
            a0 += bflo(v); a1 += bfhi(v);
        }
    }
    if (gCur >= 0) {
        atomicAdd(&out[gCur * OUT_DIM + 2 * fj], a0);
        atomicAdd(&out[gCur * OUT_DIM + 2 * fj + 1], a1);
    }
}

// ---------------- launch ----------------

extern "C" void kernel_launch(void* const* d_in, const int* in_sizes, int n_in,
                              void* d_out, int out_size, void* d_ws, size_t ws_size,
                              hipStream_t stream) {
    const float* x   = (const float*)d_in[0];
    const float* W1  = (const float*)d_in[1];
    const float* b1  = (const float*)d_in[2];
    const float* W2  = (const float*)d_in[3];
    const float* b2  = (const float*)d_in[4];
    const float* W3  = (const float*)d_in[5];
    const float* b3  = (const float*)d_in[6];
    const int* snd   = (const int*)d_in[7];
    const int* rcv   = (const int*)d_in[8];
    const int* batch = (const int*)d_in[9];
    float* out = (float*)d_out;

    char* ws = (char*)d_ws;
    size_t off = 0;
    auto carve = [&](size_t bytes) { char* p = ws + off; off += (bytes + 15) & ~size_t(15); return p; };
    int*   degS8     = (int*)  carve((size_t)NCOPY * N_NODE * 4);   // 3.2 MB
    int*   degR8     = (int*)  carve((size_t)NCOPY * N_NODE * 4);   // 3.2 MB (contiguous with degS8)
    int*   degR      = (int*)  carve(N_NODE * 4);
    int*   rowptr    = (int*)  carve((N_NODE + 1) * 4);
    int*   partials  = (int*)  carve(SCAN_BLOCKS * 4);
    unsigned char* base8 = (unsigned char*)carve((size_t)NCOPY * N_NODE);
    uint2* posP      = (uint2*)carve((size_t)(N_EDGE / 2) * 8);     // 6.4 MB
    int*   sortedSrc = (int*)  carve((size_t)N_EDGE * 4);           // 6.4 MB
    float* normS     = (float*)carve(N_NODE * 4);
    float* normR     = (float*)carve(N_NODE * 4);
    uint*  bufA      = (uint*) carve((size_t)N_NODE * 32 * 4);      // 12.8 MB (64 bf16)
    uint*  bufB      = (uint*) carve((size_t)N_NODE * 32 * 4);

    // zero the replicated histograms (contiguous at ws start) and the output
    hipMemsetAsync(d_ws, 0, (size_t)2 * NCOPY * N_NODE * 4, stream);
    hipMemsetAsync(d_out, 0, NUM_GRAPHS * OUT_DIM * 4, stream);

    k_pass1<<<EB2, 256, 0, stream>>>((const int2*)snd, (const int2*)rcv, degS8, degR8, posP);
    k_reduce<<<SCAN_BLOCKS, 256, 0, stream>>>(degS8, degR8, degR, base8, normS, normR, partials);
    k_rowptr<<<SCAN_BLOCKS, 256, 0, stream>>>(degR, partials, rowptr);
    k_pass2<<<EB2, 256, 0, stream>>>((const int2*)snd, posP, rowptr, base8, sortedSrc);

    const int AGG_B = (N_NODE * 64 + 255) / 256;   // one wave per node

    // layer 1: 128 -> 64, relu
    k_gemm_f32<IN_DIM, HID1, 16><<<(N_NODE + 15) / 16, 256, 0, stream>>>(x, W1, b1, normS, bufA);
    k_agg<HID1, true><<<AGG_B, 256, 0, stream>>>(bufA, rowptr, sortedSrc, normR, bufB);

    // layer 2: 64 -> 64, relu
    k_gemm_bf16<HID1, HID2, 16><<<(N_NODE + 15) / 16, 256, 0, stream>>>(bufB, W2, b2, normS, bufA);
    k_agg<HID2, true><<<AGG_B, 256, 0, stream>>>(bufA, rowptr, sortedSrc, normR, bufB);

    // layer 3: 64 -> 32, no relu
    k_gemm_bf16<HID2, OUT_DIM, 32><<<(N_NODE + 31) / 32, 256, 0, stream>>>(bufB, W3, b3, normS, bufA);
    k_agg<OUT_DIM, false><<<AGG_B, 256, 0, stream>>>(bufA, rowptr, sortedSrc, normR, bufB);

    // pooling
    k_pool<<<256, 256, 0, stream>>>(bufB, batch, out);
}

// Round 5
// 541.703 us; speedup vs baseline: 1.7985x; 1.1367x over previous
//
#include <hip/hip_runtime.h>
#include <hip/hip_bf16.h>

#define N_NODE   100000
#define N_EDGE   1600000
#define IN_DIM   128
#define HID1     64
#define HID2     64
#define OUT_DIM  32
#define NUM_GRAPHS 256

#define NBUCK    782            // ceil(100000/128) receiver buckets of 128 nodes
#define BBLK     500            // binning blocks
#define EPB      3200           // edges per binning block (500*3200 = 1.6M exact)
#define STAGE_CAP 4096          // LDS staging capacity in k_local (avg bucket ~2046)

typedef unsigned int uint;

__device__ __forceinline__ float bflo(uint p) { return __uint_as_float(p << 16); }
__device__ __forceinline__ float bfhi(uint p) { return __uint_as_float(p & 0xFFFF0000u); }
__device__ __forceinline__ uint bfpack(float a, float b) {
    uint ua = __float_as_uint(a), ub = __float_as_uint(b);
    ua = (ua + 0x7FFFu + ((ua >> 16) & 1u)) >> 16;
    ub = (ub + 0x7FFFu + ((ub >> 16) & 1u)) & 0xFFFF0000u;
    return ua | ub;
}

// ---------------- preprocessing: binned CSR build (no global atomics for receivers) ----------------

// count: LDS histogram over receiver buckets; degS via global atomics (overlaps LDS work)
__global__ __launch_bounds__(256)
void k_count(const int2* __restrict__ snd2, const int2* __restrict__ rcv2,
             int* __restrict__ degS, int* __restrict__ cntA) {
    __shared__ int cnt[NBUCK];
    const int t = threadIdx.x, blk = blockIdx.x;
    for (int i = t; i < NBUCK; i += 256) cnt[i] = 0;
    __syncthreads();
    const int base2 = blk * (EPB / 2);
    for (int i = 0; i < 7; ++i) {
        int local2 = i * 256 + t;
        if (local2 < EPB / 2) {
            int2 r = rcv2[base2 + local2];
            int2 s = snd2[base2 + local2];
            atomicAdd(&cnt[r.x >> 7], 1);
            atomicAdd(&cnt[r.y >> 7], 1);
            atomicAdd(&degS[s.x], 1);
            atomicAdd(&degS[s.y], 1);
        }
    }
    __syncthreads();
    for (int i = t; i < NBUCK; i += 256) cntA[blk * NBUCK + i] = cnt[i];
}

// per-bucket exclusive scan across the 500 blocks (in-place cntA -> colOff) + bucket totals
__global__ __launch_bounds__(256)
void k_scanb(int* __restrict__ cntA, int* __restrict__ bucketTotal) {
    const int b = blockIdx.x, t = threadIdx.x, lane = t & 63, wave = t >> 6;
    __shared__ int sW[4];
    int carry = 0;
    for (int k = 0; k < 2; ++k) {
        int idx = k * 256 + t;
        int v = (idx < BBLK) ? cntA[idx * NBUCK + b] : 0;
        int inc = v;
        #pragma unroll
        for (int o = 1; o < 64; o <<= 1) { int n = __shfl_up(inc, o); if (lane >= o) inc += n; }
        if (lane == 63) sW[wave] = inc;
        __syncthreads();
        int wOff = 0;
        for (int w = 0; w < wave; ++w) wOff += sW[w];
        int tot = sW[0] + sW[1] + sW[2] + sW[3];
        int excl = carry + wOff + inc - v;
        if (idx < BBLK) cntA[idx * NBUCK + b] = excl;
        carry += tot;
        __syncthreads();
    }
    if (t == 0) bucketTotal[b] = carry;
}

// scan bucket totals -> bucketBase[0..NBUCK]
__global__ __launch_bounds__(256)
void k_scanB(const int* __restrict__ bucketTotal, int* __restrict__ bucketBase) {
    const int t = threadIdx.x, lane = t & 63, wave = t >> 6;
    __shared__ int sW[4];
    int carry = 0;
    for (int k = 0; k < 4; ++k) {
        int idx = k * 256 + t;
        int v = (idx < NBUCK) ? bucketTotal[idx] : 0;
        int inc = v;
        #pragma unroll
        for (int o = 1; o < 64; o <<= 1) { int n = __shfl_up(inc, o); if (lane >= o) inc += n; }
        if (lane == 63) sW[wave] = inc;
        __syncthreads();
        int wOff = 0;
        for (int w = 0; w < wave; ++w) wOff += sW[w];
        int tot = sW[0] + sW[1] + sW[2] + sW[3];
        int excl = carry + wOff + inc - v;
        if (idx < NBUCK) bucketBase[idx] = excl;
        carry += tot;
        __syncthreads();
    }
    if (t == 0) bucketBase[NBUCK] = carry;   // = N_EDGE
}

// place edges into bucket-grouped array; packed (snd<<7)|(rcv&127)
__global__ __launch_bounds__(256)
void k_place(const int2* __restrict__ snd2, const int2* __restrict__ rcv2,
             const int* __restrict__ colOff, const int* __restrict__ bucketBase,
             uint* __restrict__ binned) {
    __shared__ int cur[NBUCK];
    const int t = threadIdx.x, blk = blockIdx.x;
    for (int i = t; i < NBUCK; i += 256) cur[i] = 0;
    __syncthreads();
    const int base2 = blk * (EPB / 2);
    for (int i = 0; i < 7; ++i) {
        int local2 = i * 256 + t;
        if (local2 < EPB / 2) {
            int2 r = rcv2[base2 + local2];
            int2 s = snd2[base2 + local2];
            int b0 = r.x >> 7, b1 = r.y >> 7;
            int l0 = atomicAdd(&cur[b0], 1);
            binned[bucketBase[b0] + colOff[blk * NBUCK + b0] + l0] = ((uint)s.x << 7) | (uint)(r.x & 127);
            int l1 = atomicAdd(&cur[b1], 1);
            binned[bucketBase[b1] + colOff[blk * NBUCK + b1] + l1] = ((uint)s.y << 7) | (uint)(r.y & 127);
        }
    }
}

// per-bucket: node histogram, local scan -> rowptr/normR/normS, contiguous placement -> sortedSrc
__global__ __launch_bounds__(256)
void k_local(const uint* __restrict__ binned, const int* __restrict__ bucketBase,
             const int* __restrict__ degS,
             int* __restrict__ rowptr, float* __restrict__ normS, float* __restrict__ normR,
             int* __restrict__ sortedSrc) {
    __shared__ uint staged[STAGE_CAP];
    __shared__ int cnt[128], excl[128], cur[128];
    const int b = blockIdx.x, t = threadIdx.x;
    const int e0 = bucketBase[b], e1 = bucketBase[b + 1], m = e1 - e0;
    if (t < 128) { cnt[t] = 0; cur[t] = 0; }
    __syncthreads();
    for (int i = t; i < m; i += 256) {
        uint v = binned[e0 + i];
        if (i < STAGE_CAP) staged[i] = v;
        atomicAdd(&cnt[v & 127u], 1);
    }
    __syncthreads();
    if (t < 64) {
        int v0 = cnt[t], v1 = cnt[64 + t];
        int i0 = v0;
        #pragma unroll
        for (int o = 1; o < 64; o <<= 1) { int n = __shfl_up(i0, o); if (t >= o) i0 += n; }
        excl[t] = i0 - v0;
        int tot0 = __shfl(i0, 63);
        int i1 = v1;
        #pragma unroll
        for (int o = 1; o < 64; o <<= 1) { int n = __shfl_up(i1, o); if (t >= o) i1 += n; }
        excl[64 + t] = tot0 + i1 - v1;
    }
    __syncthreads();
    if (t < 128) {
        int node = b * 128 + t;
        if (node < N_NODE) {
            rowptr[node] = e0 + excl[t];
            normR[node] = rsqrtf(fmaxf((float)cnt[t], 1.0f));
            normS[node] = rsqrtf(fmaxf((float)degS[node], 1.0f));
        }
    }
    if (b == NBUCK - 1 && t == 0) rowptr[N_NODE] = e1;
    for (int i = t; i < m; i += 256) {
        uint v = (i < STAGE_CAP) ? staged[i] : binned[e0 + i];
        int n7 = (int)(v & 127u);
        int lpos = atomicAdd(&cur[n7], 1);
        sortedSrc[e0 + excl[n7] + lpos] = (int)(v >> 7);
    }
}

// ---------------- dense transforms (fp32 accumulate, bf16 packed output) ----------------

template<int IN, int OUT, int NPB>
__global__ __launch_bounds__(256)
void k_gemm_f32(const float* __restrict__ X, const float* __restrict__ W,
                const float* __restrict__ bias, const float* __restrict__ normS,
                uint* __restrict__ Y2) {
    __shared__ float Wl[IN * OUT];
    __shared__ float bl[OUT];
    __shared__ float xs[NPB * IN];
    const int tid = threadIdx.x;
    for (int i = tid; i < IN * OUT; i += 256) Wl[i] = W[i];
    if (tid < OUT) bl[tid] = bias[tid];
    const int base = blockIdx.x * NPB;
    for (int i = tid; i < NPB * IN; i += 256) {
        int node = base + i / IN;
        xs[i] = (node < N_NODE) ? X[node * IN + (i % IN)] : 0.0f;
    }
    __syncthreads();
    const int wave = tid >> 6, lane = tid & 63;
    const int SUB = 64 / OUT;
    const int j = lane % OUT;
    const int sub = lane / OUT;
    const int NPW = NPB / 4;
    for (int nl = 0; nl < NPW; nl += SUB) {
        int nodeLocal = wave * NPW + nl + sub;
        int node = base + nodeLocal;
        float acc = bl[j];
        const float* xr = &xs[nodeLocal * IN];
        #pragma unroll 8
        for (int k = 0; k < IN; ++k) acc += xr[k] * Wl[k * OUT + j];
        float a = acc * ((node < N_NODE) ? normS[node] : 0.0f);
        float b = __shfl_down(a, 1);
        if (node < N_NODE && (j & 1) == 0) Y2[node * (OUT / 2) + (j >> 1)] = bfpack(a, b);
    }
}

template<int IN, int OUT, int NPB>
__global__ __launch_bounds__(256)
void k_gemm_bf16(const uint* __restrict__ X2, const float* __restrict__ W,
                 const float* __restrict__ bias, const float* __restrict__ normS,
                 uint* __restrict__ Y2) {
    __shared__ float Wl[IN * OUT];
    __shared__ float bl[OUT];
    __shared__ float xs[NPB * IN];
    const int tid = threadIdx.x;
    for (int i = tid; i < IN * OUT; i += 256) Wl[i] = W[i];
    if (tid < OUT) bl[tid] = bias[tid];
    const int base = blockIdx.x * NPB;
    const int IN2 = IN / 2;
    for (int i = tid; i < NPB * IN2; i += 256) {
        int node = base + i / IN2;
        uint p = (node < N_NODE) ? X2[node * IN2 + (i % IN2)] : 0u;
        ((float2*)xs)[i] = make_float2(bflo(p), bfhi(p));
    }
    __syncthreads();
    const int wave = tid >> 6, lane = tid & 63;
    const int SUB = 64 / OUT;
    const int j = lane % OUT;
    const int sub = lane / OUT;
    const int NPW = NPB / 4;
    for (int nl = 0; nl < NPW; nl += SUB) {
        int nodeLocal = wave * NPW + nl + sub;
        int node = base + nodeLocal;
        float acc = bl[j];
        const float* xr = &xs[nodeLocal * IN];
        #pragma unroll 8
        for (int k = 0; k < IN; ++k) acc += xr[k] * Wl[k * OUT + j];
        float a = acc * ((node < N_NODE) ? normS[node] : 0.0f);
        float b = __shfl_down(a, 1);
        if (node < N_NODE && (j & 1) == 0) Y2[node * (OUT / 2) + (j >> 1)] = bfpack(a, b);
    }
}

// ---------------- aggregation: Y[n,:] = act(normR[n] * sum_e H[src[e],:]) ; bf16 in/out ----------------

template<int F, bool RELU>
__global__ __launch_bounds__(256)
void k_agg(const uint* __restrict__ H2, const int* __restrict__ rowptr,
           const int* __restrict__ srcs, const float* __restrict__ normR,
           uint* __restrict__ Y2) {
    const int node = (blockIdx.x * 256 + threadIdx.x) >> 6;
    const int lane = threadIdx.x & 63;
    const int F2 = F / 2;
    const int PE = 64 / F2;
    const int sub = lane / F2;
    const int fj = lane % F2;
    const int start = rowptr[node], end = rowptr[node + 1];
    float a0 = 0.0f, a1 = 0.0f;
    int e = start + sub;
    for (; e + 3 * PE < end; e += 4 * PE) {
        int s0 = srcs[e], s1 = srcs[e + PE], s2 = srcs[e + 2 * PE], s3 = srcs[e + 3 * PE];
        uint p0 = H2[s0 * F2 + fj];
        uint p1 = H2[s1 * F2 + fj];
        uint p2 = H2[s2 * F2 + fj];
        uint p3 = H2[s3 * F2 + fj];
        a0 += bflo(p0); a1 += bfhi(p0);
        a0 += bflo(p1); a1 += bfhi(p1);
        a0 += bflo(p2); a1 += bfhi(p2);
        a0 += bflo(p3); a1 += bfhi(p3);
    }
    for (; e < end; e += PE) {
        uint p = H2[srcs[e] * F2 + fj];
        a0 += bflo(p); a1 += bfhi(p);
    }
    if (PE == 4) { a0 += __shfl_xor(a0, 16); a1 += __shfl_xor(a1, 16); }
    a0 += __shfl_xor(a0, 32); a1 += __shfl_xor(a1, 32);
    if (lane < F2) {
        float nr = normR[node];
        float r0 = a0 * nr, r1 = a1 * nr;
        if (RELU) { r0 = fmaxf(r0, 0.0f); r1 = fmaxf(r1, 0.0f); }
        Y2[node * F2 + fj] = bfpack(r0, r1);
    }
}

// ---------------- graph pooling (batch sorted -> run-based accumulation) ----------------

__global__ __launch_bounds__(256)
void k_pool(const uint* __restrict__ H2, const int* __restrict__ batch,
            float* __restrict__ out) {
    const int wid = (blockIdx.x * 256 + threadIdx.x) >> 6;
    const int lane = threadIdx.x & 63;
    const int NPW = (N_NODE + 1023) / 1024;
    int n0 = wid * NPW, n1 = min(n0 + NPW, N_NODE);
    const int p = lane >> 4, fj = lane & 15;
    float a0 = 0.0f, a1 = 0.0f;
    int gCur = -1;
    for (int n = n0 + p; n < n1; n += 4) {
        int g = batch[n];
        uint v = H2[n * 16 + fj];
        if (g != gCur) {
            if (gCur >= 0) {
                atomicAdd(&out[gCur * OUT_DIM + 2 * fj], a0);
                atomicAdd(&out[gCur * OUT_DIM + 2 * fj + 1], a1);
            }
            gCur = g; a0 = bflo(v); a1 = bfhi(v);
        } else {
            a0 += bflo(v); a1 += bfhi(v);
        }
    }
    if (gCur >= 0) {
        atomicAdd(&out[gCur * OUT_DIM + 2 * fj], a0);
        atomicAdd(&out[gCur * OUT_DIM + 2 * fj + 1], a1);
    }
}

// ---------------- launch ----------------

extern "C" void kernel_launch(void* const* d_in, const int* in_sizes, int n_in,
                              void* d_out, int out_size, void* d_ws, size_t ws_size,
                              hipStream_t stream) {
    const float* x   = (const float*)d_in[0];
    const float* W1  = (const float*)d_in[1];
    const float* b1  = (const float*)d_in[2];
    const float* W2  = (const float*)d_in[3];
    const float* b2  = (const float*)d_in[4];
    const float* W3  = (const float*)d_in[5];
    const float* b3  = (const float*)d_in[6];
    const int* snd   = (const int*)d_in[7];
    const int* rcv   = (const int*)d_in[8];
    const int* batch = (const int*)d_in[9];
    float* out = (float*)d_out;

    char* ws = (char*)d_ws;
    size_t off = 0;
    auto carve = [&](size_t bytes) { char* p = ws + off; off += (bytes + 15) & ~size_t(15); return p; };
    int*   degS        = (int*)  carve(N_NODE * 4);                   // zeroed below
    int*   cntA        = (int*)  carve((size_t)BBLK * NBUCK * 4);     // 1.56 MB (becomes colOff)
    int*   bucketTotal = (int*)  carve(NBUCK * 4);
    int*   bucketBase  = (int*)  carve((NBUCK + 1) * 4);
    int*   rowptr      = (int*)  carve((N_NODE + 1) * 4);
    uint*  binned      = (uint*) carve((size_t)N_EDGE * 4);           // 6.4 MB
    int*   sortedSrc   = (int*)  carve((size_t)N_EDGE * 4);           // 6.4 MB
    float* normS       = (float*)carve(N_NODE * 4);
    float* normR       = (float*)carve(N_NODE * 4);
    uint*  bufA        = (uint*) carve((size_t)N_NODE * 32 * 4);      // 12.8 MB (64 bf16)
    uint*  bufB        = (uint*) carve((size_t)N_NODE * 32 * 4);

    hipMemsetAsync(d_ws, 0, N_NODE * 4, stream);                      // degS only
    hipMemsetAsync(d_out, 0, NUM_GRAPHS * OUT_DIM * 4, stream);

    k_count<<<BBLK, 256, 0, stream>>>((const int2*)snd, (const int2*)rcv, degS, cntA);
    k_scanb<<<NBUCK, 256, 0, stream>>>(cntA, bucketTotal);
    k_scanB<<<1, 256, 0, stream>>>(bucketTotal, bucketBase);
    k_place<<<BBLK, 256, 0, stream>>>((const int2*)snd, (const int2*)rcv, cntA, bucketBase, binned);
    k_local<<<NBUCK, 256, 0, stream>>>(binned, bucketBase, degS, rowptr, normS, normR, sortedSrc);

    const int AGG_B = (N_NODE * 64 + 255) / 256;   // one wave per node

    // layer 1: 128 -> 64, relu
    k_gemm_f32<IN_DIM, HID1, 16><<<(N_NODE + 15) / 16, 256, 0, stream>>>(x, W1, b1, normS, bufA);
    k_agg<HID1, true><<<AGG_B, 256, 0, stream>>>(bufA, rowptr, sortedSrc, normR, bufB);

    // layer 2: 64 -> 64, relu
    k_gemm_bf16<HID1, HID2, 16><<<(N_NODE + 15) / 16, 256, 0, stream>>>(bufB, W2, b2, normS, bufA);
    k_agg<HID2, true><<<AGG_B, 256, 0, stream>>>(bufA, rowptr, sortedSrc, normR, bufB);

    // layer 3: 64 -> 32, no relu
    k_gemm_bf16<HID2, OUT_DIM, 32><<<(N_NODE + 31) / 32, 256, 0, stream>>>(bufB, W3, b3, normS, bufA);
    k_agg<OUT_DIM, false><<<AGG_B, 256, 0, stream>>>(bufA, rowptr, sortedSrc, normR, bufB);

    // pooling
    k_pool<<<256, 256, 0, stream>>>(bufB, batch, out);
}

// Round 8
// 419.239 us; speedup vs baseline: 2.3239x; 1.2921x over previous
//
#include <hip/hip_runtime.h>
#include <hip/hip_bf16.h>

#define N_NODE   100000
#define N_EDGE   1600000
#define IN_DIM   128
#define HID1     64
#define HID2     64
#define OUT_DIM  32
#define NUM_GRAPHS 256

#define NBUCK    782            // ceil(100000/128) receiver buckets of 128 nodes
#define BBLK     500            // binning blocks
#define EPB      3200           // edges per binning block (500*3200 = 1.6M exact)
#define STAGE_CAP 4096          // LDS staging capacity in k_local

typedef unsigned int uint;
typedef unsigned short ushort_t;
typedef short bf16x8 __attribute__((ext_vector_type(8)));
typedef float f32x4 __attribute__((ext_vector_type(4)));

__device__ __forceinline__ float bflo(uint p) { return __uint_as_float(p << 16); }
__device__ __forceinline__ float bfhi(uint p) { return __uint_as_float(p & 0xFFFF0000u); }
__device__ __forceinline__ uint bfpack(float a, float b) {
    uint ua = __float_as_uint(a), ub = __float_as_uint(b);
    ua = (ua + 0x7FFFu + ((ua >> 16) & 1u)) >> 16;
    ub = (ub + 0x7FFFu + ((ub >> 16) & 1u)) & 0xFFFF0000u;
    return ua | ub;
}
__device__ __forceinline__ ushort_t bf16r(float f) {
    uint ua = __float_as_uint(f);
    return (ushort_t)((ua + 0x7FFFu + ((ua >> 16) & 1u)) >> 16);
}

// ---------------- preprocessing: binned CSR build ----------------

__global__ __launch_bounds__(256)
void k_count(const int2* __restrict__ snd2, const int2* __restrict__ rcv2,
             int* __restrict__ degS, int* __restrict__ cntA) {
    __shared__ int cnt[NBUCK];
    const int t = threadIdx.x, blk = blockIdx.x;
    for (int i = t; i < NBUCK; i += 256) cnt[i] = 0;
    __syncthreads();
    const int base2 = blk * (EPB / 2);
    for (int i = 0; i < 7; ++i) {
        int local2 = i * 256 + t;
        if (local2 < EPB / 2) {
            int2 r = rcv2[base2 + local2];
            int2 s = snd2[base2 + local2];
            atomicAdd(&cnt[r.x >> 7], 1);
            atomicAdd(&cnt[r.y >> 7], 1);
            atomicAdd(&degS[s.x], 1);
            atomicAdd(&degS[s.y], 1);
        }
    }
    __syncthreads();
    for (int i = t; i < NBUCK; i += 256) cntA[blk * NBUCK + i] = cnt[i];
}

__global__ __launch_bounds__(256)
void k_scanb(int* __restrict__ cntA, int* __restrict__ bucketTotal) {
    const int b = blockIdx.x, t = threadIdx.x, lane = t & 63, wave = t >> 6;
    __shared__ int sW[4];
    int carry = 0;
    for (int k = 0; k < 2; ++k) {
        int idx = k * 256 + t;
        int v = (idx < BBLK) ? cntA[idx * NBUCK + b] : 0;
        int inc = v;
        #pragma unroll
        for (int o = 1; o < 64; o <<= 1) { int n = __shfl_up(inc, o); if (lane >= o) inc += n; }
        if (lane == 63) sW[wave] = inc;
        __syncthreads();
        int wOff = 0;
        for (int w = 0; w < wave; ++w) wOff += sW[w];
        int tot = sW[0] + sW[1] + sW[2] + sW[3];
        int excl = carry + wOff + inc - v;
        if (idx < BBLK) cntA[idx * NBUCK + b] = excl;
        carry += tot;
        __syncthreads();
    }
    if (t == 0) bucketTotal[b] = carry;
}

__global__ __launch_bounds__(256)
void k_scanB(const int* __restrict__ bucketTotal, int* __restrict__ bucketBase) {
    const int t = threadIdx.x, lane = t & 63, wave = t >> 6;
    __shared__ int sW[4];
    int carry = 0;
    for (int k = 0; k < 4; ++k) {
        int idx = k * 256 + t;
        int v = (idx < NBUCK) ? bucketTotal[idx] : 0;
        int inc = v;
        #pragma unroll
        for (int o = 1; o < 64; o <<= 1) { int n = __shfl_up(inc, o); if (lane >= o) inc += n; }
        if (lane == 63) sW[wave] = inc;
        __syncthreads();
        int wOff = 0;
        for (int w = 0; w < wave; ++w) wOff += sW[w];
        int tot = sW[0] + sW[1] + sW[2] + sW[3];
        int excl = carry + wOff + inc - v;
        if (idx < NBUCK) bucketBase[idx] = excl;
        carry += tot;
        __syncthreads();
    }
    if (t == 0) bucketBase[NBUCK] = carry;
}

__global__ __launch_bounds__(256)
void k_place(const int2* __restrict__ snd2, const int2* __restrict__ rcv2,
             const int* __restrict__ colOff, const int* __restrict__ bucketBase,
             uint* __restrict__ binned) {
    __shared__ int cur[NBUCK];
    const int t = threadIdx.x, blk = blockIdx.x;
    for (int i = t; i < NBUCK; i += 256) cur[i] = 0;
    __syncthreads();
    const int base2 = blk * (EPB / 2);
    for (int i = 0; i < 7; ++i) {
        int local2 = i * 256 + t;
        if (local2 < EPB / 2) {
            int2 r = rcv2[base2 + local2];
            int2 s = snd2[base2 + local2];
            int b0 = r.x >> 7, b1 = r.y >> 7;
            int l0 = atomicAdd(&cur[b0], 1);
            binned[bucketBase[b0] + colOff[blk * NBUCK + b0] + l0] = ((uint)s.x << 7) | (uint)(r.x & 127);
            int l1 = atomicAdd(&cur[b1], 1);
            binned[bucketBase[b1] + colOff[blk * NBUCK + b1] + l1] = ((uint)s.y << 7) | (uint)(r.y & 127);
        }
    }
}

__global__ __launch_bounds__(256)
void k_local(const uint* __restrict__ binned, const int* __restrict__ bucketBase,
             const int* __restrict__ degS,
             int* __restrict__ rowptr, float* __restrict__ normS, float* __restrict__ normR,
             int* __restrict__ sortedSrc) {
    __shared__ uint staged[STAGE_CAP];
    __shared__ int cnt[128], excl[128], cur[128];
    const int b = blockIdx.x, t = threadIdx.x;
    const int e0 = bucketBase[b], e1 = bucketBase[b + 1], m = e1 - e0;
    if (t < 128) { cnt[t] = 0; cur[t] = 0; }
    __syncthreads();
    for (int i = t; i < m; i += 256) {
        uint v = binned[e0 + i];
        if (i < STAGE_CAP) staged[i] = v;
        atomicAdd(&cnt[v & 127u], 1);
    }
    __syncthreads();
    if (t < 64) {
        int v0 = cnt[t], v1 = cnt[64 + t];
        int i0 = v0;
        #pragma unroll
        for (int o = 1; o < 64; o <<= 1) { int n = __shfl_up(i0, o); if (t >= o) i0 += n; }
        excl[t] = i0 - v0;
        int tot0 = __shfl(i0, 63);
        int i1 = v1;
        #pragma unroll
        for (int o = 1; o < 64; o <<= 1) { int n = __shfl_up(i1, o); if (t >= o) i1 += n; }
        excl[64 + t] = tot0 + i1 - v1;
    }
    __syncthreads();
    if (t < 128) {
        int node = b * 128 + t;
        if (node < N_NODE) {
            rowptr[node] = e0 + excl[t];
            normR[node] = rsqrtf(fmaxf((float)cnt[t], 1.0f));
            normS[node] = rsqrtf(fmaxf((float)degS[node], 1.0f));
        }
    }
    if (b == NBUCK - 1 && t == 0) rowptr[N_NODE] = e1;
    for (int i = t; i < m; i += 256) {
        uint v = (i < STAGE_CAP) ? staged[i] : binned[e0 + i];
        int n7 = (int)(v & 127u);
        int lpos = atomicAdd(&cur[n7], 1);
        sortedSrc[e0 + excl[n7] + lpos] = (int)(v >> 7);
    }
}

// ---------------- weight prep: Wt[col][k] = bf16(W[k][col]) ----------------

__global__ __launch_bounds__(256)
void k_prepw(const float* __restrict__ W1, const float* __restrict__ W2,
             const float* __restrict__ W3,
             ushort_t* __restrict__ Wt1, ushort_t* __restrict__ Wt2,
             ushort_t* __restrict__ Wt3) {
    int i = blockIdx.x * 256 + threadIdx.x;
    if (i < 8192) {                       // 64 cols x 128 k
        int col = i >> 7, k = i & 127;
        Wt1[i] = bf16r(W1[k * 64 + col]);
    } else if (i < 12288) {               // 64 cols x 64 k
        int j = i - 8192; int col = j >> 6, k = j & 63;
        Wt2[j] = bf16r(W2[k * 64 + col]);
    } else if (i < 14336) {               // 32 cols x 64 k
        int j = i - 12288; int col = j >> 6, k = j & 63;
        Wt3[j] = bf16r(W3[k * 32 + col]);
    }
}

// ---------------- MFMA dense transform: Y[n,:] = (X[n,:] @ W + b) * normS[n] ----------------
// 16x16x32 bf16 MFMA; block = 4 waves = 64 nodes; LDS-swizzled Wt (T2-style XOR)

template<int K, int N, bool F32IN>
__global__ __launch_bounds__(256)
void k_mgemm(const void* __restrict__ Xv, const ushort_t* __restrict__ Wt,
             const float* __restrict__ bias, const float* __restrict__ normS,
             uint* __restrict__ Y2) {
    __shared__ uint WL[N * K / 2];
    const int tid = threadIdx.x, wave = tid >> 6, lane = tid & 63;
    const uint* Wg = (const uint*)Wt;
    for (int i = tid; i < N * K / 2; i += 256) {
        int col = i / (K / 2);
        WL[i ^ ((col & 7) << 2)] = Wg[i];
    }
    const int m0 = blockIdx.x * 64 + wave * 16;
    const int arow = m0 + (lane & 15);
    const int asrc = (arow < N_NODE) ? arow : 0;
    const int koff = (lane >> 4) * 8;
    bf16x8 afr[K / 32];
    if (F32IN) {
        const float* Xf = (const float*)Xv + (size_t)asrc * K + koff;
        #pragma unroll
        for (int s = 0; s < K / 32; ++s) {
            float4 u = *(const float4*)(Xf + 32 * s);
            float4 v = *(const float4*)(Xf + 32 * s + 4);
            union { uint u4[4]; bf16x8 v8; } c;
            c.u4[0] = bfpack(u.x, u.y); c.u4[1] = bfpack(u.z, u.w);
            c.u4[2] = bfpack(v.x, v.y); c.u4[3] = bfpack(v.z, v.w);
            afr[s] = c.v8;
        }
    } else {
        const uint* Xp = (const uint*)Xv + (size_t)asrc * (K / 2) + (koff >> 1);
        #pragma unroll
        for (int s = 0; s < K / 32; ++s) {
            uint2 q0 = *(const uint2*)(Xp + 16 * s);
            uint2 q1 = *(const uint2*)(Xp + 16 * s + 2);
            union { uint u4[4]; bf16x8 v8; } c;
            c.u4[0] = q0.x; c.u4[1] = q0.y; c.u4[2] = q1.x; c.u4[3] = q1.y;
            afr[s] = c.v8;
        }
    }
    __syncthreads();
    f32x4 acc[N / 16];
    #pragma unroll
    for (int t = 0; t < N / 16; ++t) acc[t] = (f32x4){0.f, 0.f, 0.f, 0.f};
    #pragma unroll
    for (int s = 0; s < K / 32; ++s) {
        #pragma unroll
        for (int t = 0; t < N / 16; ++t) {
            int col = t * 16 + (lane & 15);
            int word = (col * (K / 2) + s * 16 + (koff >> 1)) ^ ((col & 7) << 2);
            bf16x8 bfr = *(const bf16x8*)&WL[word];
            acc[t] = __builtin_amdgcn_mfma_f32_16x16x32_bf16(afr[s], bfr, acc[t], 0, 0, 0);
        }
    }
    const int r0 = m0 + (lane >> 4) * 4;
    float ns[4];
    #pragma unroll
    for (int i = 0; i < 4; ++i) ns[i] = (r0 + i < N_NODE) ? normS[r0 + i] : 0.f;
    #pragma unroll
    for (int t = 0; t < N / 16; ++t) {
        int col = t * 16 + (lane & 15);
        float bv = bias[col];
        #pragma unroll
        for (int i = 0; i < 4; ++i) {
            float v = (acc[t][i] + bv) * ns[i];
            float w = __shfl_down(v, 1);
            if ((lane & 1) == 0 && r0 + i < N_NODE)
                Y2[(size_t)(r0 + i) * (N / 2) + (col >> 1)] = bfpack(v, w);
        }
    }
}

// ---------------- aggregation: Y[n,:] = act(normR[n] * sum_e H[src[e],:]) ; bf16 in/out ----------------

template<int F, bool RELU>
__global__ __launch_bounds__(256)
void k_agg(const uint* __restrict__ H2, const int* __restrict__ rowptr,
           const int* __restrict__ srcs, const float* __restrict__ normR,
           uint* __restrict__ Y2) {
    const int node = (blockIdx.x * 256 + threadIdx.x) >> 6;
    const int lane = threadIdx.x & 63;
    const int F2 = F / 2;
    const int PE = 64 / F2;
    const int sub = lane / F2;
    const int fj = lane % F2;
    const int start = rowptr[node], end = rowptr[node + 1];
    float a0 = 0.0f, a1 = 0.0f;
    int e = start + sub;
    for (; e + 3 * PE < end; e += 4 * PE) {
        int s0 = srcs[e], s1 = srcs[e + PE], s2 = srcs[e + 2 * PE], s3 = srcs[e + 3 * PE];
        uint p0 = H2[s0 * F2 + fj];
        uint p1 = H2[s1 * F2 + fj];
        uint p2 = H2[s2 * F2 + fj];
        uint p3 = H2[s3 * F2 + fj];
        a0 += bflo(p0); a1 += bfhi(p0);
        a0 += bflo(p1); a1 += bfhi(p1);
        a0 += bflo(p2); a1 += bfhi(p2);
        a0 += bflo(p3); a1 += bfhi(p3);
    }
    for (; e < end; e += PE) {
        uint p = H2[srcs[e] * F2 + fj];
        a0 += bflo(p); a1 += bfhi(p);
    }
    if (PE == 4) { a0 += __shfl_xor(a0, 16); a1 += __shfl_xor(a1, 16); }
    a0 += __shfl_xor(a0, 32); a1 += __shfl_xor(a1, 32);
    if (lane < F2) {
        float nr = normR[node];
        float r0 = a0 * nr, r1 = a1 * nr;
        if (RELU) { r0 = fmaxf(r0, 0.0f); r1 = fmaxf(r1, 0.0f); }
        Y2[node * F2 + fj] = bfpack(r0, r1);
    }
}

// ---------------- graph pooling (batch sorted -> run-based accumulation) ----------------

__global__ __launch_bounds__(256)
void k_pool(const uint* __restrict__ H2, const int* __restrict__ batch,
            float* __restrict__ out) {
    const int wid = (blockIdx.x * 256 + threadIdx.x) >> 6;
    const int lane = threadIdx.x & 63;
    const int NPW = (N_NODE + 1023) / 1024;
    int n0 = wid * NPW, n1 = min(n0 + NPW, N_NODE);
    const int p = lane >> 4, fj = lane & 15;
    float a0 = 0.0f, a1 = 0.0f;
    int gCur = -1;
    for (int n = n0 + p; n < n1; n += 4) {
        int g = batch[n];
        uint v = H2[n * 16 + fj];
        if (g != gCur) {
            if (gCur >= 0) {
                atomicAdd(&out[gCur * OUT_DIM + 2 * fj], a0);
                atomicAdd(&out[gCur * OUT_DIM + 2 * fj + 1], a1);
            }
            gCur = g; a0 = bflo(v); a1 = bfhi(v);
        } else {
            a0 += bflo(v); a1 += bfhi(v);
        }
    }
    if (gCur >= 0) {
        atomicAdd(&out[gCur * OUT_DIM + 2 * fj], a0);
        atomicAdd(&out[gCur * OUT_DIM + 2 * fj + 1], a1);
    }
}

// ---------------- launch ----------------

extern "C" void kernel_launch(void* const* d_in, const int* in_sizes, int n_in,
                              void* d_out, int out_size, void* d_ws, size_t ws_size,
                              hipStream_t stream) {
    const float* x   = (const float*)d_in[0];
    const float* W1  = (const float*)d_in[1];
    const float* b1  = (const float*)d_in[2];
    const float* W2  = (const float*)d_in[3];
    const float* b2  = (const float*)d_in[4];
    const float* W3  = (const float*)d_in[5];
    const float* b3  = (const float*)d_in[6];
    const int* snd   = (const int*)d_in[7];
    const int* rcv   = (const int*)d_in[8];
    const int* batch = (const int*)d_in[9];
    float* out = (float*)d_out;

    char* ws = (char*)d_ws;
    size_t off = 0;
    auto carve = [&](size_t bytes) { char* p = ws + off; off += (bytes + 15) & ~size_t(15); return p; };
    int*   degS        = (int*)  carve(N_NODE * 4);                   // zeroed below
    int*   cntA        = (int*)  carve((size_t)BBLK * NBUCK * 4);     // becomes colOff
    int*   bucketTotal = (int*)  carve(NBUCK * 4);
    int*   bucketBase  = (int*)  carve((NBUCK + 1) * 4);
    int*   rowptr      = (int*)  carve((N_NODE + 1) * 4);
    uint*  binned      = (uint*) carve((size_t)N_EDGE * 4);
    int*   sortedSrc   = (int*)  carve((size_t)N_EDGE * 4);
    float* normS       = (float*)carve(N_NODE * 4);
    float* normR       = (float*)carve(N_NODE * 4);
    ushort_t* Wt1      = (ushort_t*)carve(8192 * 2);
    ushort_t* Wt2      = (ushort_t*)carve(4096 * 2);
    ushort_t* Wt3      = (ushort_t*)carve(2048 * 2);
    uint*  bufA        = (uint*) carve((size_t)N_NODE * 32 * 4);
    uint*  bufB        = (uint*) carve((size_t)N_NODE * 32 * 4);

    hipMemsetAsync(d_ws, 0, N_NODE * 4, stream);                      // degS only
    hipMemsetAsync(d_out, 0, NUM_GRAPHS * OUT_DIM * 4, stream);

    k_prepw<<<56, 256, 0, stream>>>(W1, W2, W3, Wt1, Wt2, Wt3);
    k_count<<<BBLK, 256, 0, stream>>>((const int2*)snd, (const int2*)rcv, degS, cntA);
    k_scanb<<<NBUCK, 256, 0, stream>>>(cntA, bucketTotal);
    k_scanB<<<1, 256, 0, stream>>>(bucketTotal, bucketBase);
    k_place<<<BBLK, 256, 0, stream>>>((const int2*)snd, (const int2*)rcv, cntA, bucketBase, binned);
    k_local<<<NBUCK, 256, 0, stream>>>(binned, bucketBase, degS, rowptr, normS, normR, sortedSrc);

    const int AGG_B = (N_NODE * 64 + 255) / 256;   // one wave per node
    const int GB = (N_NODE + 63) / 64;             // 1563 MFMA blocks

    // layer 1: 128 -> 64, relu
    k_mgemm<IN_DIM, HID1, true><<<GB, 256, 0, stream>>>(x, Wt1, b1, normS, bufA);
    k_agg<HID1, true><<<AGG_B, 256, 0, stream>>>(bufA, rowptr, sortedSrc, normR, bufB);

    // layer 2: 64 -> 64, relu
    k_mgemm<HID1, HID2, false><<<GB, 256, 0, stream>>>(bufB, Wt2, b2, normS, bufA);
    k_agg<HID2, true><<<AGG_B, 256, 0, stream>>>(bufA, rowptr, sortedSrc, normR, bufB);

    // layer 3: 64 -> 32, no relu
    k_mgemm<HID2, OUT_DIM, false><<<GB, 256, 0, stream>>>(bufB, Wt3, b3, normS, bufA);
    k_agg<OUT_DIM, false><<<AGG_B, 256, 0, stream>>>(bufA, rowptr, sortedSrc, normR, bufB);

    // pooling
    k_pool<<<256, 256, 0, stream>>>(bufB, batch, out);
}

// Round 9
// 380.076 us; speedup vs baseline: 2.5633x; 1.1030x over previous
//
#include <hip/hip_runtime.h>
#include <hip/hip_bf16.h>

#define N_NODE   100000
#define N_EDGE   1600000
#define IN_DIM   128
#define HID1     64
#define HID2     64
#define OUT_DIM  32
#define NUM_GRAPHS 256

#define NBUCK    782            // ceil(100000/128) node buckets of 128
#define BBLK     500            // binning blocks
#define EPB      3200           // edges per binning block (500*3200 = 1.6M exact)
#define STAGE_CAP 4096          // LDS staging capacity in k_local

typedef unsigned int uint;
typedef unsigned char uchar;
typedef unsigned short ushort_t;
typedef short bf16x8 __attribute__((ext_vector_type(8)));
typedef float f32x4 __attribute__((ext_vector_type(4)));

__device__ __forceinline__ float bflo(uint p) { return __uint_as_float(p << 16); }
__device__ __forceinline__ float bfhi(uint p) { return __uint_as_float(p & 0xFFFF0000u); }
__device__ __forceinline__ uint bfpack(float a, float b) {
    uint ua = __float_as_uint(a), ub = __float_as_uint(b);
    ua = (ua + 0x7FFFu + ((ua >> 16) & 1u)) >> 16;
    ub = (ub + 0x7FFFu + ((ub >> 16) & 1u)) & 0xFFFF0000u;
    return ua | ub;
}
__device__ __forceinline__ ushort_t bf16r(float f) {
    uint ua = __float_as_uint(f);
    return (ushort_t)((ua + 0x7FFFu + ((ua >> 16) & 1u)) >> 16);
}

// ---------------- preprocessing: binned CSR build (zero global atomics) ----------------

// count: LDS histograms over receiver AND sender buckets
__global__ __launch_bounds__(256)
void k_count(const int2* __restrict__ snd2, const int2* __restrict__ rcv2,
             int* __restrict__ cntRA, int* __restrict__ cntSA) {
    __shared__ int cntR[NBUCK];
    __shared__ int cntS[NBUCK];
    const int t = threadIdx.x, blk = blockIdx.x;
    for (int i = t; i < NBUCK; i += 256) { cntR[i] = 0; cntS[i] = 0; }
    __syncthreads();
    const int base2 = blk * (EPB / 2);
    for (int i = 0; i < 7; ++i) {
        int local2 = i * 256 + t;
        if (local2 < EPB / 2) {
            int2 r = rcv2[base2 + local2];
            int2 s = snd2[base2 + local2];
            atomicAdd(&cntR[r.x >> 7], 1);
            atomicAdd(&cntR[r.y >> 7], 1);
            atomicAdd(&cntS[s.x >> 7], 1);
            atomicAdd(&cntS[s.y >> 7], 1);
        }
    }
    __syncthreads();
    for (int i = t; i < NBUCK; i += 256) {
        cntRA[blk * NBUCK + i] = cntR[i];
        cntSA[blk * NBUCK + i] = cntS[i];
    }
}

// per-bucket exclusive scan across blocks, for R (which=0) and S (which=1)
__global__ __launch_bounds__(256)
void k_scanb(int* __restrict__ cntRA, int* __restrict__ cntSA,
             int* __restrict__ rTotal, int* __restrict__ sTotal) {
    const int which = blockIdx.x / NBUCK;
    const int b = blockIdx.x % NBUCK;
    int* cntA = which ? cntSA : cntRA;
    int* total = which ? sTotal : rTotal;
    const int t = threadIdx.x, lane = t & 63, wave = t >> 6;
    __shared__ int sW[4];
    int carry = 0;
    for (int k = 0; k < 2; ++k) {
        int idx = k * 256 + t;
        int v = (idx < BBLK) ? cntA[idx * NBUCK + b] : 0;
        int inc = v;
        #pragma unroll
        for (int o = 1; o < 64; o <<= 1) { int n = __shfl_up(inc, o); if (lane >= o) inc += n; }
        if (lane == 63) sW[wave] = inc;
        __syncthreads();
        int wOff = 0;
        for (int w = 0; w < wave; ++w) wOff += sW[w];
        int tot = sW[0] + sW[1] + sW[2] + sW[3];
        int excl = carry + wOff + inc - v;
        if (idx < BBLK) cntA[idx * NBUCK + b] = excl;
        carry += tot;
        __syncthreads();
    }
    if (t == 0) total[b] = carry;
}

// scan bucket totals -> base arrays; block 0: receiver, block 1: sender
__global__ __launch_bounds__(256)
void k_scanB(const int* __restrict__ rTotal, const int* __restrict__ sTotal,
             int* __restrict__ rBase, int* __restrict__ sBase) {
    const int* total = blockIdx.x ? sTotal : rTotal;
    int* base = blockIdx.x ? sBase : rBase;
    const int t = threadIdx.x, lane = t & 63, wave = t >> 6;
    __shared__ int sW[4];
    int carry = 0;
    for (int k = 0; k < 4; ++k) {
        int idx = k * 256 + t;
        int v = (idx < NBUCK) ? total[idx] : 0;
        int inc = v;
        #pragma unroll
        for (int o = 1; o < 64; o <<= 1) { int n = __shfl_up(inc, o); if (lane >= o) inc += n; }
        if (lane == 63) sW[wave] = inc;
        __syncthreads();
        int wOff = 0;
        for (int w = 0; w < wave; ++w) wOff += sW[w];
        int tot = sW[0] + sW[1] + sW[2] + sW[3];
        int excl = carry + wOff + inc - v;
        if (idx < NBUCK) base[idx] = excl;
        carry += tot;
        __syncthreads();
    }
    if (t == 0) base[NBUCK] = carry;
}

// place: receiver-binned uint (snd<<7|rcv&127) + sender-binned byte (snd&127)
__global__ __launch_bounds__(256)
void k_place(const int2* __restrict__ snd2, const int2* __restrict__ rcv2,
             const int* __restrict__ rColOff, const int* __restrict__ sColOff,
             const int* __restrict__ rBase, const int* __restrict__ sBase,
             uint* __restrict__ binned, uchar* __restrict__ sBin) {
    __shared__ int curR[NBUCK];
    __shared__ int curS[NBUCK];
    const int t = threadIdx.x, blk = blockIdx.x;
    for (int i = t; i < NBUCK; i += 256) { curR[i] = 0; curS[i] = 0; }
    __syncthreads();
    const int base2 = blk * (EPB / 2);
    for (int i = 0; i < 7; ++i) {
        int local2 = i * 256 + t;
        if (local2 < EPB / 2) {
            int2 r = rcv2[base2 + local2];
            int2 s = snd2[base2 + local2];
            int b0 = r.x >> 7, b1 = r.y >> 7;
            int l0 = atomicAdd(&curR[b0], 1);
            binned[rBase[b0] + rColOff[blk * NBUCK + b0] + l0] = ((uint)s.x << 7) | (uint)(r.x & 127);
            int l1 = atomicAdd(&curR[b1], 1);
            binned[rBase[b1] + rColOff[blk * NBUCK + b1] + l1] = ((uint)s.y << 7) | (uint)(r.y & 127);
            int c0 = s.x >> 7, c1 = s.y >> 7;
            int m0 = atomicAdd(&curS[c0], 1);
            sBin[sBase[c0] + sColOff[blk * NBUCK + c0] + m0] = (uchar)(s.x & 127);
            int m1 = atomicAdd(&curS[c1], 1);
            sBin[sBase[c1] + sColOff[blk * NBUCK + c1] + m1] = (uchar)(s.y & 127);
        }
    }
}

// per-bucket: node histograms (recv + send), local scan -> rowptr/normR/normS, place sortedSrc
__global__ __launch_bounds__(256)
void k_local(const uint* __restrict__ binned, const uchar* __restrict__ sBin,
             const int* __restrict__ rBase, const int* __restrict__ sBase,
             int* __restrict__ rowptr, float* __restrict__ normS, float* __restrict__ normR,
             int* __restrict__ sortedSrc) {
    __shared__ uint staged[STAGE_CAP];
    __shared__ int cnt[128], excl[128], cur[128], cntS2[128];
    const int b = blockIdx.x, t = threadIdx.x;
    const int e0 = rBase[b], e1 = rBase[b + 1], m = e1 - e0;
    const int s0 = sBase[b], s1 = sBase[b + 1], ms = s1 - s0;
    if (t < 128) { cnt[t] = 0; cur[t] = 0; cntS2[t] = 0; }
    __syncthreads();
    for (int i = t; i < m; i += 256) {
        uint v = binned[e0 + i];
        if (i < STAGE_CAP) staged[i] = v;
        atomicAdd(&cnt[v & 127u], 1);
    }
    for (int i = t; i < ms; i += 256) {
        atomicAdd(&cntS2[(int)sBin[s0 + i]], 1);
    }
    __syncthreads();
    if (t < 64) {
        int v0 = cnt[t], v1 = cnt[64 + t];
        int i0 = v0;
        #pragma unroll
        for (int o = 1; o < 64; o <<= 1) { int n = __shfl_up(i0, o); if (t >= o) i0 += n; }
        excl[t] = i0 - v0;
        int tot0 = __shfl(i0, 63);
        int i1 = v1;
        #pragma unroll
        for (int o = 1; o < 64; o <<= 1) { int n = __shfl_up(i1, o); if (t >= o) i1 += n; }
        excl[64 + t] = tot0 + i1 - v1;
    }
    __syncthreads();
    if (t < 128) {
        int node = b * 128 + t;
        if (node < N_NODE) {
            rowptr[node] = e0 + excl[t];
            normR[node] = rsqrtf(fmaxf((float)cnt[t], 1.0f));
            normS[node] = rsqrtf(fmaxf((float)cntS2[t], 1.0f));
        }
    }
    if (b == NBUCK - 1 && t == 0) rowptr[N_NODE] = e1;
    for (int i = t; i < m; i += 256) {
        uint v = (i < STAGE_CAP) ? staged[i] : binned[e0 + i];
        int n7 = (int)(v & 127u);
        int lpos = atomicAdd(&cur[n7], 1);
        sortedSrc[e0 + excl[n7] + lpos] = (int)(v >> 7);
    }
}

// ---------------- weight prep: Wt[col][k] = bf16(W[k][col]) ----------------

__global__ __launch_bounds__(256)
void k_prepw(const float* __restrict__ W1, const float* __restrict__ W2,
             const float* __restrict__ W3,
             ushort_t* __restrict__ Wt1, ushort_t* __restrict__ Wt2,
             ushort_t* __restrict__ Wt3) {
    int i = blockIdx.x * 256 + threadIdx.x;
    if (i < 8192) {                       // 64 cols x 128 k
        int col = i >> 7, k = i & 127;
        Wt1[i] = bf16r(W1[k * 64 + col]);
    } else if (i < 12288) {               // 64 cols x 64 k
        int j = i - 8192; int col = j >> 6, k = j & 63;
        Wt2[j] = bf16r(W2[k * 64 + col]);
    } else if (i < 14336) {               // 32 cols x 64 k
        int j = i - 12288; int col = j >> 6, k = j & 63;
        Wt3[j] = bf16r(W3[k * 32 + col]);
    }
}

// ---------------- MFMA dense transform: Y[n,:] = (X[n,:] @ W + b) * normS[n] ----------------

template<int K, int N, bool F32IN>
__global__ __launch_bounds__(256)
void k_mgemm(const void* __restrict__ Xv, const ushort_t* __restrict__ Wt,
             const float* __restrict__ bias, const float* __restrict__ normS,
             uint* __restrict__ Y2) {
    __shared__ uint WL[N * K / 2];
    const int tid = threadIdx.x, wave = tid >> 6, lane = tid & 63;
    const uint* Wg = (const uint*)Wt;
    for (int i = tid; i < N * K / 2; i += 256) {
        int col = i / (K / 2);
        WL[i ^ ((col & 7) << 2)] = Wg[i];
    }
    const int m0 = blockIdx.x * 64 + wave * 16;
    const int arow = m0 + (lane & 15);
    const int asrc = (arow < N_NODE) ? arow : 0;
    const int koff = (lane >> 4) * 8;
    bf16x8 afr[K / 32];
    if (F32IN) {
        const float* Xf = (const float*)Xv + (size_t)asrc * K + koff;
        #pragma unroll
        for (int s = 0; s < K / 32; ++s) {
            float4 u = *(const float4*)(Xf + 32 * s);
            float4 v = *(const float4*)(Xf + 32 * s + 4);
            union { uint u4[4]; bf16x8 v8; } c;
            c.u4[0] = bfpack(u.x, u.y); c.u4[1] = bfpack(u.z, u.w);
            c.u4[2] = bfpack(v.x, v.y); c.u4[3] = bfpack(v.z, v.w);
            afr[s] = c.v8;
        }
    } else {
        const uint* Xp = (const uint*)Xv + (size_t)asrc * (K / 2) + (koff >> 1);
        #pragma unroll
        for (int s = 0; s < K / 32; ++s) {
            uint2 q0 = *(const uint2*)(Xp + 16 * s);
            uint2 q1 = *(const uint2*)(Xp + 16 * s + 2);
            union { uint u4[4]; bf16x8 v8; } c;
            c.u4[0] = q0.x; c.u4[1] = q0.y; c.u4[2] = q1.x; c.u4[3] = q1.y;
            afr[s] = c.v8;
        }
    }
    __syncthreads();
    f32x4 acc[N / 16];
    #pragma unroll
    for (int t = 0; t < N / 16; ++t) acc[t] = (f32x4){0.f, 0.f, 0.f, 0.f};
    #pragma unroll
    for (int s = 0; s < K / 32; ++s) {
        #pragma unroll
        for (int t = 0; t < N / 16; ++t) {
            int col = t * 16 + (lane & 15);
            int word = (col * (K / 2) + s * 16 + (koff >> 1)) ^ ((col & 7) << 2);
            bf16x8 bfr = *(const bf16x8*)&WL[word];
            acc[t] = __builtin_amdgcn_mfma_f32_16x16x32_bf16(afr[s], bfr, acc[t], 0, 0, 0);
        }
    }
    const int r0 = m0 + (lane >> 4) * 4;
    float ns[4];
    #pragma unroll
    for (int i = 0; i < 4; ++i) ns[i] = (r0 + i < N_NODE) ? normS[r0 + i] : 0.f;
    #pragma unroll
    for (int t = 0; t < N / 16; ++t) {
        int col = t * 16 + (lane & 15);
        float bv = bias[col];
        #pragma unroll
        for (int i = 0; i < 4; ++i) {
            float v = (acc[t][i] + bv) * ns[i];
            float w = __shfl_down(v, 1);
            if ((lane & 1) == 0 && r0 + i < N_NODE)
                Y2[(size_t)(r0 + i) * (N / 2) + (col >> 1)] = bfpack(v, w);
        }
    }
}

// ---------------- aggregation: Y[n,:] = act(normR[n] * sum_e H[src[e],:]) ; bf16 in/out ----------------

template<int F, bool RELU>
__global__ __launch_bounds__(256)
void k_agg(const uint* __restrict__ H2, const int* __restrict__ rowptr,
           const int* __restrict__ srcs, const float* __restrict__ normR,
           uint* __restrict__ Y2) {
    const int node = (blockIdx.x * 256 + threadIdx.x) >> 6;
    const int lane = threadIdx.x & 63;
    const int F2 = F / 2;
    const int PE = 64 / F2;
    const int sub = lane / F2;
    const int fj = lane % F2;
    const int start = rowptr[node], end = rowptr[node + 1];
    float a0 = 0.0f, a1 = 0.0f;
    int e = start + sub;
    for (; e + 3 * PE < end; e += 4 * PE) {
        int s0 = srcs[e], s1 = srcs[e + PE], s2 = srcs[e + 2 * PE], s3 = srcs[e + 3 * PE];
        uint p0 = H2[s0 * F2 + fj];
        uint p1 = H2[s1 * F2 + fj];
        uint p2 = H2[s2 * F2 + fj];
        uint p3 = H2[s3 * F2 + fj];
        a0 += bflo(p0); a1 += bfhi(p0);
        a0 += bflo(p1); a1 += bfhi(p1);
        a0 += bflo(p2); a1 += bfhi(p2);
        a0 += bflo(p3); a1 += bfhi(p3);
    }
    for (; e < end; e += PE) {
        uint p = H2[srcs[e] * F2 + fj];
        a0 += bflo(p); a1 += bfhi(p);
    }
    if (PE == 4) { a0 += __shfl_xor(a0, 16); a1 += __shfl_xor(a1, 16); }
    a0 += __shfl_xor(a0, 32); a1 += __shfl_xor(a1, 32);
    if (lane < F2) {
        float nr = normR[node];
        float r0 = a0 * nr, r1 = a1 * nr;
        if (RELU) { r0 = fmaxf(r0, 0.0f); r1 = fmaxf(r1, 0.0f); }
        Y2[node * F2 + fj] = bfpack(r0, r1);
    }
}

// ---------------- graph pooling (batch sorted -> run-based accumulation) ----------------

__global__ __launch_bounds__(256)
void k_pool(const uint* __restrict__ H2, const int* __restrict__ batch,
            float* __restrict__ out) {
    const int wid = (blockIdx.x * 256 + threadIdx.x) >> 6;
    const int lane = threadIdx.x & 63;
    const int NPW = (N_NODE + 1023) / 1024;
    int n0 = wid * NPW, n1 = min(n0 + NPW, N_NODE);
    const int p = lane >> 4, fj = lane & 15;
    float a0 = 0.0f, a1 = 0.0f;
    int gCur = -1;
    for (int n = n0 + p; n < n1; n += 4) {
        int g = batch[n];
        uint v = H2[n * 16 + fj];
        if (g != gCur) {
            if (gCur >= 0) {
                atomicAdd(&out[gCur * OUT_DIM + 2 * fj], a0);
                atomicAdd(&out[gCur * OUT_DIM + 2 * fj + 1], a1);
            }
            gCur = g; a0 = bflo(v); a1 = bfhi(v);
        } else {
            a0 += bflo(v); a1 += bfhi(v);
        }
    }
    if (gCur >= 0) {
        atomicAdd(&out[gCur * OUT_DIM + 2 * fj], a0);
        atomicAdd(&out[gCur * OUT_DIM + 2 * fj + 1], a1);
    }
}

// ---------------- launch ----------------

extern "C" void kernel_launch(void* const* d_in, const int* in_sizes, int n_in,
                              void* d_out, int out_size, void* d_ws, size_t ws_size,
                              hipStream_t stream) {
    const float* x   = (const float*)d_in[0];
    const float* W1  = (const float*)d_in[1];
    const float* b1  = (const float*)d_in[2];
    const float* W2  = (const float*)d_in[3];
    const float* b2  = (const float*)d_in[4];
    const float* W3  = (const float*)d_in[5];
    const float* b3  = (const float*)d_in[6];
    const int* snd   = (const int*)d_in[7];
    const int* rcv   = (const int*)d_in[8];
    const int* batch = (const int*)d_in[9];
    float* out = (float*)d_out;

    char* ws = (char*)d_ws;
    size_t off = 0;
    auto carve = [&](size_t bytes) { char* p = ws + off; off += (bytes + 15) & ~size_t(15); return p; };
    int*   cntRA       = (int*)  carve((size_t)BBLK * NBUCK * 4);     // becomes rColOff
    int*   cntSA       = (int*)  carve((size_t)BBLK * NBUCK * 4);     // becomes sColOff
    int*   rTotal      = (int*)  carve(NBUCK * 4);
    int*   sTotal      = (int*)  carve(NBUCK * 4);
    int*   rBase       = (int*)  carve((NBUCK + 1) * 4);
    int*   sBase       = (int*)  carve((NBUCK + 1) * 4);
    int*   rowptr      = (int*)  carve((N_NODE + 1) * 4);
    uint*  binned      = (uint*) carve((size_t)N_EDGE * 4);
    uchar* sBin        = (uchar*)carve((size_t)N_EDGE);
    int*   sortedSrc   = (int*)  carve((size_t)N_EDGE * 4);
    float* normS       = (float*)carve(N_NODE * 4);
    float* normR       = (float*)carve(N_NODE * 4);
    ushort_t* Wt1      = (ushort_t*)carve(8192 * 2);
    ushort_t* Wt2      = (ushort_t*)carve(4096 * 2);
    ushort_t* Wt3      = (ushort_t*)carve(2048 * 2);
    uint*  bufA        = (uint*) carve((size_t)N_NODE * 32 * 4);
    uint*  bufB        = (uint*) carve((size_t)N_NODE * 32 * 4);

    hipMemsetAsync(d_out, 0, NUM_GRAPHS * OUT_DIM * 4, stream);

    k_prepw<<<56, 256, 0, stream>>>(W1, W2, W3, Wt1, Wt2, Wt3);
    k_count<<<BBLK, 256, 0, stream>>>((const int2*)snd, (const int2*)rcv, cntRA, cntSA);
    k_scanb<<<2 * NBUCK, 256, 0, stream>>>(cntRA, cntSA, rTotal, sTotal);
    k_scanB<<<2, 256, 0, stream>>>(rTotal, sTotal, rBase, sBase);
    k_place<<<BBLK, 256, 0, stream>>>((const int2*)snd, (const int2*)rcv, cntRA, cntSA,
                                      rBase, sBase, binned, sBin);
    k_local<<<NBUCK, 256, 0, stream>>>(binned, sBin, rBase, sBase,
                                       rowptr, normS, normR, sortedSrc);

    const int AGG_B = (N_NODE * 64 + 255) / 256;   // one wave per node
    const int GB = (N_NODE + 63) / 64;             // MFMA blocks

    // layer 1: 128 -> 64, relu
    k_mgemm<IN_DIM, HID1, true><<<GB, 256, 0, stream>>>(x, Wt1, b1, normS, bufA);
    k_agg<HID1, true><<<AGG_B, 256, 0, stream>>>(bufA, rowptr, sortedSrc, normR, bufB);

    // layer 2: 64 -> 64, relu
    k_mgemm<HID1, HID2, false><<<GB, 256, 0, stream>>>(bufB, Wt2, b2, normS, bufA);
    k_agg<HID2, true><<<AGG_B, 256, 0, stream>>>(bufA, rowptr, sortedSrc, normR, bufB);

    // layer 3: 64 -> 32, no relu
    k_mgemm<HID2, OUT_DIM, false><<<GB, 256, 0, stream>>>(bufB, Wt3, b3, normS, bufA);
    k_agg<OUT_DIM, false><<<AGG_B, 256, 0, stream>>>(bufA, rowptr, sortedSrc, normR, bufB);

    // pooling
    k_pool<<<256, 256, 0, stream>>>(bufB, batch, out);
}